// Round 11
// baseline (205.775 us; speedup 1.0000x reference)
//
#include <hip/hip_runtime.h>
#include <math.h>

#define NB 24
#define DM 128
#define NH 8
#define DK 16
#define LL 512
#define HB (NH * NB)   // 192

// MEASUREMENT ROUND: every kernel repeats its body `reps` times (runtime arg,
// idempotent, output ptrs NOT __restrict so the compiler must re-execute).
// Dispatch durations in rocprof = reps * true cost -> rises above the ~43us
// harness fill dispatches that have hidden per-kernel attribution for 2 rounds.

// ---------------------------------------------------------------------------
// Workspace layout (BYTES), ~31 MB total:
//   xThi/xTlo [NB][LL][DM] ushort : x transposed, split bf16 (B-frag layout)
//   Whi/Wlo   [HB*3][16][128]     : W split bf16 (A-frag layout), idx hb*3+mat
//   Wob       [NB][128][128]      : Wo plain bf16
//   qb/kb     [HB][LL][32]        : split rows, [0:16]=hi [16:32]=lo;
//                                   K pre-scaled by 0.25*log2e
//   vb        [HB][DK][LL]        : V plain bf16
//   headT     [NB][LL][DM]        : attention out, bf16, B-frag layout for Wo
// ---------------------------------------------------------------------------
#define XTH_OFF 0
#define XTL_OFF 3145728
#define WHI_OFF 6291456
#define WLO_OFF 8650752
#define WOB_OFF 11010048
#define QB_OFF  11796480
#define KB_OFF  18087936
#define VB_OFF  24379392
#define HT_OFF  27525120

typedef __attribute__((ext_vector_type(8))) short bf16x8;
typedef __attribute__((ext_vector_type(4))) float f32x4;
typedef __attribute__((ext_vector_type(4))) int   i32x4;

#define MFMA  __builtin_amdgcn_mfma_f32_16x16x32_bf16
#define EXP2  __builtin_amdgcn_exp2f
#define BPERM __builtin_amdgcn_ds_bpermute

static __device__ __forceinline__ unsigned bfr(float x) {
    return (__float_as_uint(x) + 0x8000u) & 0xffff0000u;
}
static __device__ __forceinline__ unsigned pk2(unsigned e, unsigned o) {
    return (e >> 16) | o;
}

// ---------------------------------------------------------------------------
// Kernel 0: prep. 1440 blocks:
//   [0,768)      x -> xThi/xTlo: (b, lc of 16 l), LDS 128x17 fp32 (8.7 KB).
//                (round-10 used 192 blocks = 0.75/CU — occupancy hole)
//   [768,1344)   W split, w=bid-768: hb=w/3 mat=w%3
//   [1344,1440)  Wo -> bf16
// ---------------------------------------------------------------------------
__global__ __launch_bounds__(256)
void prep(const float* __restrict__ x,
          const float* __restrict__ Wq,
          const float* __restrict__ Wk,
          const float* __restrict__ Wv,
          const float* __restrict__ Wo,
          unsigned short* xthi,
          unsigned short* xtlo,
          unsigned short* whi,
          unsigned short* wlo,
          unsigned short* wob,
          int reps)
{
    __shared__ float T[128][17];
    const int bid = blockIdx.x, tid = threadIdx.x;

    #pragma unroll 1
    for (int rep = 0; rep < reps; ++rep) {
        if (bid < 768) {
            const int b = bid >> 5, lc = bid & 31;
            const int l0 = lc * 16;
            #pragma unroll
            for (int i = 0; i < 8; ++i) {             // 2048 loads, 64B runs
                const int idx = i * 256 + tid;
                const int d = idx >> 4, l = idx & 15;
                T[d][l] = x[(size_t)b * 65536 + (size_t)d * LL + l0 + l];
            }
            __syncthreads();
            #pragma unroll
            for (int i = 0; i < 8; ++i) {             // coalesced along d
                const int idx = i * 256 + tid;
                const int l = idx >> 7, d = idx & 127;
                const float v = T[d][l];              // +1 pad: conflict-free
                const unsigned h = bfr(v);
                const size_t o = (size_t)b * 65536 + (size_t)(l0 + l) * DM + d;
                xthi[o] = (unsigned short)(h >> 16);
                xtlo[o] = (unsigned short)(bfr(v - __uint_as_float(h)) >> 16);
            }
            __syncthreads();                          // WAR guard for next rep
        } else if (bid < 1344) {
            const int w = bid - 768, hb = w / 3, mat = w - hb * 3;
            const float* __restrict__ src =
                (mat == 0 ? Wq : (mat == 1 ? Wk : Wv)) + (size_t)hb * 2048;
            unsigned short* dh = whi + (size_t)w * 2048;
            unsigned short* dl = wlo + (size_t)w * 2048;
            for (int i = tid; i < 2048; i += 256) {
                const float v = src[i];
                const unsigned h = bfr(v);
                dh[i] = (unsigned short)(h >> 16);
                dl[i] = (unsigned short)(bfr(v - __uint_as_float(h)) >> 16);
            }
        } else {
            const int w = bid - 1344;
            const float* __restrict__ src = Wo + (size_t)w * 4096;
            unsigned short* d = wob + (size_t)w * 4096;
            for (int i = tid; i < 4096; i += 256)
                d[i] = (unsigned short)(bfr(src[i]) >> 16);
        }
    }
}

// ---------------------------------------------------------------------------
// Kernel 1: QKV projection on MFMA. 1152 blocks = (hb*3+mat, nc) x 4 waves.
// Split product via 3 MFMAs (lo*lo dropped, ~2^-16 rel).
// ---------------------------------------------------------------------------
__global__ __launch_bounds__(256)
void qkv_mfma(const unsigned short* __restrict__ xthi,
              const unsigned short* __restrict__ xtlo,
              const unsigned short* __restrict__ whi,
              const unsigned short* __restrict__ wlo,
              unsigned short* qb,
              unsigned short* kb,
              unsigned short* vb,
              int reps)
{
    const int blk  = blockIdx.x;
    const int nc   = blk & 1;
    const int hm   = blk >> 1;
    const int mat  = hm % 3;
    const int hb   = hm / 3;
    const int b    = hb % NB;
    const int wv   = threadIdx.x >> 6;
    const int lane = threadIdx.x & 63;
    const int g = lane >> 4, mR = lane & 15;
    const int l0 = nc * 256 + wv * 64;

    const unsigned short* __restrict__ wA = whi + (size_t)hm * 2048 + mR * 128 + g * 8;
    const unsigned short* __restrict__ wB = wlo + (size_t)hm * 2048 + mR * 128 + g * 8;
    const unsigned short* __restrict__ xh = xthi + (size_t)b * 65536 + g * 8;
    const unsigned short* __restrict__ xl = xtlo + (size_t)b * 65536 + g * 8;

    #pragma unroll 1
    for (int rep = 0; rep < reps; ++rep) {
        f32x4 C[4];
        #pragma unroll
        for (int t = 0; t < 4; ++t) C[t] = (f32x4){0.f, 0.f, 0.f, 0.f};

        #pragma unroll
        for (int kk = 0; kk < 4; ++kk) {
            const bf16x8 aH = *(const bf16x8*)(wA + kk * 32);
            const bf16x8 aL = *(const bf16x8*)(wB + kk * 32);
            #pragma unroll
            for (int t = 0; t < 4; ++t) {
                const size_t lo_ = (size_t)(l0 + t * 16 + mR) * DM + kk * 32;
                const bf16x8 bH = *(const bf16x8*)(xh + lo_);
                const bf16x8 bL = *(const bf16x8*)(xl + lo_);
                C[t] = MFMA(aH, bH, C[t], 0, 0, 0);
                C[t] = MFMA(aH, bL, C[t], 0, 0, 0);
                C[t] = MFMA(aL, bH, C[t], 0, 0, 0);
            }
        }

        if (mat == 2) {
            unsigned short* vo = vb + (size_t)hb * 8192;
            #pragma unroll
            for (int t = 0; t < 4; ++t) {
                const int l = l0 + t * 16 + mR;
                #pragma unroll
                for (int i = 0; i < 4; ++i)
                    vo[(size_t)(4 * g + i) * LL + l] =
                        (unsigned short)(bfr(C[t][i]) >> 16);
            }
        } else {
            const float scale = (mat == 1) ? (0.25f * 1.44269504f) : 1.0f;
            unsigned short* dst = (mat == 0 ? qb : kb) + (size_t)hb * LL * 32;
            #pragma unroll
            for (int t = 0; t < 4; ++t) {
                const int l = l0 + t * 16 + mR;
                ushort4 hi4, lo4;
                #pragma unroll
                for (int i = 0; i < 4; ++i) {
                    const float v = C[t][i] * scale;
                    const unsigned h = bfr(v);
                    const unsigned lw = bfr(v - __uint_as_float(h));
                    ((unsigned short*)&hi4)[i] = (unsigned short)(h >> 16);
                    ((unsigned short*)&lo4)[i] = (unsigned short)(lw >> 16);
                }
                *(ushort4*)(dst + (size_t)l * 32 + 4 * g)      = hi4;
                *(ushort4*)(dst + (size_t)l * 32 + 16 + 4 * g) = lo4;
            }
        }
    }
}

// ---------------------------------------------------------------------------
// Kernel 2: MFMA flash attention. ROUND-11: 8-way m-split -> 1536 blocks =
// (hb, mc of 64 m) x 4 waves; wave owns ONE 16-m tile (round-10: 2 tiles,
// 768 blocks, 12 waves/CU). Occupancy doubles to 24 waves/CU.
// ---------------------------------------------------------------------------
static __device__ __forceinline__ void soft_pv(
    const f32x4& s0, const f32x4& s1, float tm, float& bar, float& sm,
    f32x4& O, const bf16x8& aV, int aLo, int aHi, bool up)
{
    const float nb = fmaxf(bar, tm + 32.f);
    const float f  = EXP2(bar - nb);
    bar = nb;
    const unsigned u0 = bfr(EXP2(s0[0]-nb)), u1 = bfr(EXP2(s0[1]-nb));
    const unsigned u2 = bfr(EXP2(s0[2]-nb)), u3 = bfr(EXP2(s0[3]-nb));
    const unsigned w0 = bfr(EXP2(s1[0]-nb)), w1 = bfr(EXP2(s1[1]-nb));
    const unsigned w2 = bfr(EXP2(s1[2]-nb)), w3 = bfr(EXP2(s1[3]-nb));
    const float sacc =
        ((__uint_as_float(u0) + __uint_as_float(u1)) +
         (__uint_as_float(u2) + __uint_as_float(u3))) +
        ((__uint_as_float(w0) + __uint_as_float(w1)) +
         (__uint_as_float(w2) + __uint_as_float(w3)));
    sm = fmaf(sm, f, sacc);
    O *= f;
    const int c0 = (int)pk2(u0, u1), c1 = (int)pk2(u2, u3);
    const int c2 = (int)pk2(w0, w1), c3 = (int)pk2(w2, w3);
    const int p00 = BPERM(aLo, c0), p02 = BPERM(aLo, c2);
    const int p10 = BPERM(aLo, c1), p12 = BPERM(aLo, c3);
    const int p20 = BPERM(aHi, c0), p22 = BPERM(aHi, c2);
    const int p30 = BPERM(aHi, c1), p32 = BPERM(aHi, c3);
    i32x4 bi = { up ? p00 : p02, up ? p10 : p12,
                 up ? p20 : p22, up ? p30 : p32 };
    O = MFMA(aV, __builtin_bit_cast(bf16x8, bi), O, 0, 0, 0);
}

__global__ __launch_bounds__(256)
void attn_mfma(const unsigned short* __restrict__ qb,
               const unsigned short* __restrict__ kb,
               const unsigned short* __restrict__ vb,
               unsigned short* ht,
               int reps)
{
    const int hb   = blockIdx.x >> 3;
    const int mc   = blockIdx.x & 7;
    const int tid  = threadIdx.x;
    const int wave = tid >> 6;
    const int lane = tid & 63;
    const int g    = lane >> 4;
    const int mR   = lane & 15;
    const int mb   = mc * 64 + wave * 16;

    const unsigned short* Kr0 = kb + ((size_t)hb * LL + mb + mR) * 32;
    const bf16x8 bK0  = *(const bf16x8*)(Kr0 + g * 8);
    const bf16x8 bK0s = *(const bf16x8*)(Kr0 + (g ^ 2) * 8);

    const unsigned short* qrow = qb + ((size_t)hb * LL + mR) * 32 + g * 8;
    const unsigned short* vrow = vb + ((size_t)hb * DK + mR) * LL + g * 8;

    const int aLo = ((g & 1) * 32 + mR) * 4;
    const int aHi = aLo + 64;
    const bool up = (g < 2);

    const int h = hb / NB, bb = hb % NB;
    unsigned short* ho =
        ht + (size_t)bb * 65536 + (size_t)(mb + mR) * DM + h * 16 + 4 * g;

    #pragma unroll 1
    for (int rep = 0; rep < reps; ++rep) {
        f32x4 O0 = {0.f,0.f,0.f,0.f};
        float bar0 = -1e30f, sm0 = 0.f;

        for (int l = 0; l < LL; l += 32) {
            const bf16x8 aQ0 = *(const bf16x8*)(qrow + (size_t)l * 32);
            const bf16x8 aQ1 = *(const bf16x8*)(qrow + (size_t)(l + 16) * 32);

            const f32x4 z = {0.f,0.f,0.f,0.f};
            f32x4 sA0 = MFMA(aQ0, bK0, z, 0,0,0);  sA0 = MFMA(aQ0, bK0s, sA0, 0,0,0);
            f32x4 sA1 = MFMA(aQ1, bK0, z, 0,0,0);  sA1 = MFMA(aQ1, bK0s, sA1, 0,0,0);

            float tmA = fmaxf(fmaxf(fmaxf(sA0[0],sA0[1]), fmaxf(sA0[2],sA0[3])),
                              fmaxf(fmaxf(sA1[0],sA1[1]), fmaxf(sA1[2],sA1[3])));
            tmA = fmaxf(tmA, __shfl_xor(tmA, 16, 64));
            tmA = fmaxf(tmA, __shfl_xor(tmA, 32, 64));

            if (__any(tmA + 64.f > bar0)) {
                const bf16x8 aV = *(const bf16x8*)(vrow + l);
                soft_pv(sA0, sA1, tmA, bar0, sm0, O0, aV, aLo, aHi, up);
            }
        }

        sm0 += __shfl_xor(sm0, 16, 64);  sm0 += __shfl_xor(sm0, 32, 64);
        const float i0 = 1.f / sm0;

        ushort4 p0;
        #pragma unroll
        for (int i = 0; i < 4; ++i)
            ((unsigned short*)&p0)[i] = (unsigned short)(bfr(O0[i] * i0) >> 16);
        *(ushort4*)ho = p0;
    }
}

// ---------------------------------------------------------------------------
// Kernel 3: out = Wo @ headT on MFMA. 768 blocks.
// ---------------------------------------------------------------------------
__global__ __launch_bounds__(256)
void out_mfma(const unsigned short* __restrict__ wob,
              const unsigned short* __restrict__ ht,
              float* out,
              int reps)
{
    const int blk  = blockIdx.x;
    const int b    = blk >> 5;
    const int mq   = (blk >> 4) & 1;
    const int nq   = blk & 15;
    const int wv   = threadIdx.x >> 6;
    const int lane = threadIdx.x & 63;
    const int g = lane >> 4, mR = lane & 15;
    const int m0 = (mq * 4 + wv) * 16;
    const int n0 = nq * 32;

    const unsigned short* __restrict__ A =
        wob + (size_t)b * 16384 + (size_t)(m0 + mR) * DM + g * 8;
    const unsigned short* __restrict__ B = ht + (size_t)b * 65536 + g * 8;

    #pragma unroll 1
    for (int rep = 0; rep < reps; ++rep) {
        f32x4 C0 = {0.f,0.f,0.f,0.f}, C1 = {0.f,0.f,0.f,0.f};
        #pragma unroll
        for (int kk = 0; kk < 4; ++kk) {
            const bf16x8 aW = *(const bf16x8*)(A + kk * 32);
            const bf16x8 b0 = *(const bf16x8*)(B + (size_t)(n0 + mR) * DM + kk * 32);
            const bf16x8 b1 = *(const bf16x8*)(B + (size_t)(n0 + 16 + mR) * DM + kk * 32);
            C0 = MFMA(aW, b0, C0, 0, 0, 0);
            C1 = MFMA(aW, b1, C1, 0, 0, 0);
        }

        float* ob = out + (size_t)b * 65536 + (size_t)(m0 + 4 * g) * LL;
        #pragma unroll
        for (int i = 0; i < 4; ++i) {
            ob[(size_t)i * LL + n0 + mR]      = C0[i];
            ob[(size_t)i * LL + n0 + 16 + mR] = C1[i];
        }
    }
}

extern "C" void kernel_launch(void* const* d_in, const int* in_sizes, int n_in,
                              void* d_out, int out_size, void* d_ws, size_t ws_size,
                              hipStream_t stream) {
    const float* x  = (const float*)d_in[0];
    const float* Wq = (const float*)d_in[1];
    const float* Wk = (const float*)d_in[2];
    const float* Wv = (const float*)d_in[3];
    const float* Wo = (const float*)d_in[4];
    float* out = (float*)d_out;

    char* ws = (char*)d_ws;
    unsigned short* xthi = (unsigned short*)(ws + XTH_OFF);
    unsigned short* xtlo = (unsigned short*)(ws + XTL_OFF);
    unsigned short* whi  = (unsigned short*)(ws + WHI_OFF);
    unsigned short* wlo  = (unsigned short*)(ws + WLO_OFF);
    unsigned short* wob  = (unsigned short*)(ws + WOB_OFF);
    unsigned short* qb   = (unsigned short*)(ws + QB_OFF);
    unsigned short* kb   = (unsigned short*)(ws + KB_OFF);
    unsigned short* vb   = (unsigned short*)(ws + VB_OFF);
    unsigned short* ht   = (unsigned short*)(ws + HT_OFF);

    const int REPS = 4;   // measurement amplifier — remove next round

    prep     <<<1440,    256, 0, stream>>>(x, Wq, Wk, Wv, Wo, xthi, xtlo, whi, wlo, wob, REPS);
    qkv_mfma <<<HB * 6,  256, 0, stream>>>(xthi, xtlo, whi, wlo, qb, kb, vb, REPS);
    attn_mfma<<<HB * 8,  256, 0, stream>>>(qb, kb, vb, ht, REPS);
    out_mfma <<<NB * 32, 256, 0, stream>>>(wob, ht, out, REPS);
}

// Round 12
// 127.588 us; speedup vs baseline: 1.6128x; 1.6128x over previous
//
#include <hip/hip_runtime.h>
#include <math.h>

#define NB 24
#define DM 128
#define NH 8
#define DK 16
#define LL 512
#define HB (NH * NB)   // 192

// ---------------------------------------------------------------------------
// Measured true costs (round-11 REPS=4 amplification): attn_mfma ~25.6 us
// (VALUBusy 65%, MfmaUtil 12.8% -> VALU-issue-bound on softmax bookkeeping);
// prep+qkv+out ~26 us combined. This round: REPS removed; attn P-pack
// truncation (v_perm-matchable) replaces round+mask+shift-or (24->~12 ops/step).
//
// Workspace layout (BYTES), ~31 MB total:
//   xThi/xTlo [NB][LL][DM] ushort : x transposed, split bf16 (B-frag layout)
//   Whi/Wlo   [HB*3][16][128]     : W split bf16 (A-frag layout), idx hb*3+mat
//   Wob       [NB][128][128]      : Wo plain bf16
//   qb/kb     [HB][LL][32]        : split rows, [0:16]=hi [16:32]=lo;
//                                   K pre-scaled by 0.25*log2e
//   vb        [HB][DK][LL]        : V plain bf16
//   headT     [NB][LL][DM]        : attention out, bf16, B-frag layout for Wo
// ---------------------------------------------------------------------------
#define XTH_OFF 0
#define XTL_OFF 3145728
#define WHI_OFF 6291456
#define WLO_OFF 8650752
#define WOB_OFF 11010048
#define QB_OFF  11796480
#define KB_OFF  18087936
#define VB_OFF  24379392
#define HT_OFF  27525120

typedef __attribute__((ext_vector_type(8))) short bf16x8;
typedef __attribute__((ext_vector_type(4))) float f32x4;
typedef __attribute__((ext_vector_type(4))) int   i32x4;

#define MFMA  __builtin_amdgcn_mfma_f32_16x16x32_bf16
#define EXP2  __builtin_amdgcn_exp2f
#define BPERM __builtin_amdgcn_ds_bpermute

static __device__ __forceinline__ unsigned bfr(float x) {
    return (__float_as_uint(x) + 0x8000u) & 0xffff0000u;
}
static __device__ __forceinline__ unsigned pk2(unsigned e, unsigned o) {
    return (e >> 16) | o;
}
// truncation pack of two fp32 -> bf16x2 dword; backend fuses to v_perm_b32
static __device__ __forceinline__ int pkt(float e, float o) {
    return (int)((__float_as_uint(o) & 0xffff0000u) | (__float_as_uint(e) >> 16));
}

// ---------------------------------------------------------------------------
// Kernel 0: prep. 1440 blocks:
//   [0,768)      x -> xThi/xTlo: (b, lc of 16 l), LDS 128x17 fp32 (8.7 KB)
//   [768,1344)   W split, w=bid-768: hb=w/3 mat=w%3
//   [1344,1440)  Wo -> bf16
// ---------------------------------------------------------------------------
__global__ __launch_bounds__(256)
void prep(const float* __restrict__ x,
          const float* __restrict__ Wq,
          const float* __restrict__ Wk,
          const float* __restrict__ Wv,
          const float* __restrict__ Wo,
          unsigned short* __restrict__ xthi,
          unsigned short* __restrict__ xtlo,
          unsigned short* __restrict__ whi,
          unsigned short* __restrict__ wlo,
          unsigned short* __restrict__ wob)
{
    __shared__ float T[128][17];
    const int bid = blockIdx.x, tid = threadIdx.x;

    if (bid < 768) {
        const int b = bid >> 5, lc = bid & 31;
        const int l0 = lc * 16;
        #pragma unroll
        for (int i = 0; i < 8; ++i) {
            const int idx = i * 256 + tid;
            const int d = idx >> 4, l = idx & 15;
            T[d][l] = x[(size_t)b * 65536 + (size_t)d * LL + l0 + l];
        }
        __syncthreads();
        #pragma unroll
        for (int i = 0; i < 8; ++i) {
            const int idx = i * 256 + tid;
            const int l = idx >> 7, d = idx & 127;
            const float v = T[d][l];
            const unsigned h = bfr(v);
            const size_t o = (size_t)b * 65536 + (size_t)(l0 + l) * DM + d;
            xthi[o] = (unsigned short)(h >> 16);
            xtlo[o] = (unsigned short)(bfr(v - __uint_as_float(h)) >> 16);
        }
    } else if (bid < 1344) {
        const int w = bid - 768, hb = w / 3, mat = w - hb * 3;
        const float* __restrict__ src =
            (mat == 0 ? Wq : (mat == 1 ? Wk : Wv)) + (size_t)hb * 2048;
        unsigned short* __restrict__ dh = whi + (size_t)w * 2048;
        unsigned short* __restrict__ dl = wlo + (size_t)w * 2048;
        for (int i = tid; i < 2048; i += 256) {
            const float v = src[i];
            const unsigned h = bfr(v);
            dh[i] = (unsigned short)(h >> 16);
            dl[i] = (unsigned short)(bfr(v - __uint_as_float(h)) >> 16);
        }
    } else {
        const int w = bid - 1344;
        const float* __restrict__ src = Wo + (size_t)w * 4096;
        unsigned short* __restrict__ d = wob + (size_t)w * 4096;
        for (int i = tid; i < 4096; i += 256)
            d[i] = (unsigned short)(bfr(src[i]) >> 16);
    }
}

// ---------------------------------------------------------------------------
// Kernel 1: QKV projection on MFMA. 1152 blocks = (hb*3+mat, nc) x 4 waves.
// Split product via 3 MFMAs (lo*lo dropped, ~2^-16 rel).
// ---------------------------------------------------------------------------
__global__ __launch_bounds__(256)
void qkv_mfma(const unsigned short* __restrict__ xthi,
              const unsigned short* __restrict__ xtlo,
              const unsigned short* __restrict__ whi,
              const unsigned short* __restrict__ wlo,
              unsigned short* __restrict__ qb,
              unsigned short* __restrict__ kb,
              unsigned short* __restrict__ vb)
{
    const int blk  = blockIdx.x;
    const int nc   = blk & 1;
    const int hm   = blk >> 1;
    const int mat  = hm % 3;
    const int hb   = hm / 3;
    const int b    = hb % NB;
    const int wv   = threadIdx.x >> 6;
    const int lane = threadIdx.x & 63;
    const int g = lane >> 4, mR = lane & 15;
    const int l0 = nc * 256 + wv * 64;

    const unsigned short* __restrict__ wA = whi + (size_t)hm * 2048 + mR * 128 + g * 8;
    const unsigned short* __restrict__ wB = wlo + (size_t)hm * 2048 + mR * 128 + g * 8;
    const unsigned short* __restrict__ xh = xthi + (size_t)b * 65536 + g * 8;
    const unsigned short* __restrict__ xl = xtlo + (size_t)b * 65536 + g * 8;

    f32x4 C[4];
    #pragma unroll
    for (int t = 0; t < 4; ++t) C[t] = (f32x4){0.f, 0.f, 0.f, 0.f};

    #pragma unroll
    for (int kk = 0; kk < 4; ++kk) {
        const bf16x8 aH = *(const bf16x8*)(wA + kk * 32);
        const bf16x8 aL = *(const bf16x8*)(wB + kk * 32);
        #pragma unroll
        for (int t = 0; t < 4; ++t) {
            const size_t lo_ = (size_t)(l0 + t * 16 + mR) * DM + kk * 32;
            const bf16x8 bH = *(const bf16x8*)(xh + lo_);
            const bf16x8 bL = *(const bf16x8*)(xl + lo_);
            C[t] = MFMA(aH, bH, C[t], 0, 0, 0);
            C[t] = MFMA(aH, bL, C[t], 0, 0, 0);
            C[t] = MFMA(aL, bH, C[t], 0, 0, 0);
        }
    }

    if (mat == 2) {
        unsigned short* __restrict__ vo = vb + (size_t)hb * 8192;
        #pragma unroll
        for (int t = 0; t < 4; ++t) {
            const int l = l0 + t * 16 + mR;
            #pragma unroll
            for (int i = 0; i < 4; ++i)
                vo[(size_t)(4 * g + i) * LL + l] =
                    (unsigned short)(bfr(C[t][i]) >> 16);
        }
    } else {
        const float scale = (mat == 1) ? (0.25f * 1.44269504f) : 1.0f;
        unsigned short* __restrict__ dst =
            (mat == 0 ? qb : kb) + (size_t)hb * LL * 32;
        #pragma unroll
        for (int t = 0; t < 4; ++t) {
            const int l = l0 + t * 16 + mR;
            ushort4 hi4, lo4;
            #pragma unroll
            for (int i = 0; i < 4; ++i) {
                const float v = C[t][i] * scale;
                const unsigned h = bfr(v);
                const unsigned lw = bfr(v - __uint_as_float(h));
                ((unsigned short*)&hi4)[i] = (unsigned short)(h >> 16);
                ((unsigned short*)&lo4)[i] = (unsigned short)(lw >> 16);
            }
            *(ushort4*)(dst + (size_t)l * 32 + 4 * g)      = hi4;
            *(ushort4*)(dst + (size_t)l * 32 + 16 + 4 * g) = lo4;
        }
    }
}

// ---------------------------------------------------------------------------
// Kernel 2: MFMA flash attention. 1536 blocks = (hb, mc of 64 m) x 4 waves;
// wave owns one 16-m tile. ROUND-12: P packed by TRUNCATION via
// (o&0xffff0000)|(e>>16) (v_perm-matchable, replaces round+mask+shr+or:
// 24->12 ops/step); denominator sums raw fp32 p (+0.2% systematic, ~0.1-0.5
// absolute on output — negligible vs 13.6 threshold).
// ---------------------------------------------------------------------------
static __device__ __forceinline__ void soft_pv(
    const f32x4& s0, const f32x4& s1, float tm, float& bar, float& sm,
    f32x4& O, const bf16x8& aV, int aLo, int aHi, bool up)
{
    const float nb = fmaxf(bar, tm + 32.f);
    const float f  = EXP2(bar - nb);
    bar = nb;
    const float p0 = EXP2(s0[0]-nb), p1 = EXP2(s0[1]-nb);
    const float p2 = EXP2(s0[2]-nb), p3 = EXP2(s0[3]-nb);
    const float q0 = EXP2(s1[0]-nb), q1 = EXP2(s1[1]-nb);
    const float q2 = EXP2(s1[2]-nb), q3 = EXP2(s1[3]-nb);
    sm = fmaf(sm, f, ((p0 + p1) + (p2 + p3)) + ((q0 + q1) + (q2 + q3)));
    O *= f;
    const int c0 = pkt(p0, p1), c1 = pkt(p2, p3);
    const int c2 = pkt(q0, q1), c3 = pkt(q2, q3);
    const int p00 = BPERM(aLo, c0), p02 = BPERM(aLo, c2);
    const int p10 = BPERM(aLo, c1), p12 = BPERM(aLo, c3);
    const int p20 = BPERM(aHi, c0), p22 = BPERM(aHi, c2);
    const int p30 = BPERM(aHi, c1), p32 = BPERM(aHi, c3);
    i32x4 bi = { up ? p00 : p02, up ? p10 : p12,
                 up ? p20 : p22, up ? p30 : p32 };
    O = MFMA(aV, __builtin_bit_cast(bf16x8, bi), O, 0, 0, 0);
}

__global__ __launch_bounds__(256)
void attn_mfma(const unsigned short* __restrict__ qb,
               const unsigned short* __restrict__ kb,
               const unsigned short* __restrict__ vb,
               unsigned short* __restrict__ ht)
{
    const int hb   = blockIdx.x >> 3;
    const int mc   = blockIdx.x & 7;
    const int tid  = threadIdx.x;
    const int wave = tid >> 6;
    const int lane = tid & 63;
    const int g    = lane >> 4;
    const int mR   = lane & 15;
    const int mb   = mc * 64 + wave * 16;

    const unsigned short* Kr0 = kb + ((size_t)hb * LL + mb + mR) * 32;
    const bf16x8 bK0  = *(const bf16x8*)(Kr0 + g * 8);
    const bf16x8 bK0s = *(const bf16x8*)(Kr0 + (g ^ 2) * 8);

    const unsigned short* qrow = qb + ((size_t)hb * LL + mR) * 32 + g * 8;
    const unsigned short* vrow = vb + ((size_t)hb * DK + mR) * LL + g * 8;

    const int aLo = ((g & 1) * 32 + mR) * 4;
    const int aHi = aLo + 64;
    const bool up = (g < 2);

    f32x4 O0 = {0.f,0.f,0.f,0.f};
    float bar0 = -1e30f, sm0 = 0.f;

    for (int l = 0; l < LL; l += 32) {
        const bf16x8 aQ0 = *(const bf16x8*)(qrow + (size_t)l * 32);
        const bf16x8 aQ1 = *(const bf16x8*)(qrow + (size_t)(l + 16) * 32);

        const f32x4 z = {0.f,0.f,0.f,0.f};
        f32x4 sA0 = MFMA(aQ0, bK0, z, 0,0,0);  sA0 = MFMA(aQ0, bK0s, sA0, 0,0,0);
        f32x4 sA1 = MFMA(aQ1, bK0, z, 0,0,0);  sA1 = MFMA(aQ1, bK0s, sA1, 0,0,0);

        float tmA = fmaxf(fmaxf(fmaxf(sA0[0],sA0[1]), fmaxf(sA0[2],sA0[3])),
                          fmaxf(fmaxf(sA1[0],sA1[1]), fmaxf(sA1[2],sA1[3])));
        tmA = fmaxf(tmA, __shfl_xor(tmA, 16, 64));
        tmA = fmaxf(tmA, __shfl_xor(tmA, 32, 64));

        if (__any(tmA + 64.f > bar0)) {
            const bf16x8 aV = *(const bf16x8*)(vrow + l);
            soft_pv(sA0, sA1, tmA, bar0, sm0, O0, aV, aLo, aHi, up);
        }
    }

    sm0 += __shfl_xor(sm0, 16, 64);  sm0 += __shfl_xor(sm0, 32, 64);
    const float i0 = 1.f / sm0;

    const int h = hb / NB, bb = hb % NB;
    unsigned short* __restrict__ ho =
        ht + (size_t)bb * 65536 + (size_t)(mb + mR) * DM + h * 16 + 4 * g;
    ushort4 p0;
    #pragma unroll
    for (int i = 0; i < 4; ++i)
        ((unsigned short*)&p0)[i] = (unsigned short)(bfr(O0[i] * i0) >> 16);
    *(ushort4*)ho = p0;
}

// ---------------------------------------------------------------------------
// Kernel 3: out = Wo @ headT on MFMA. 768 blocks.
// ---------------------------------------------------------------------------
__global__ __launch_bounds__(256)
void out_mfma(const unsigned short* __restrict__ wob,
              const unsigned short* __restrict__ ht,
              float* __restrict__ out)
{
    const int blk  = blockIdx.x;
    const int b    = blk >> 5;
    const int mq   = (blk >> 4) & 1;
    const int nq   = blk & 15;
    const int wv   = threadIdx.x >> 6;
    const int lane = threadIdx.x & 63;
    const int g = lane >> 4, mR = lane & 15;
    const int m0 = (mq * 4 + wv) * 16;
    const int n0 = nq * 32;

    const unsigned short* __restrict__ A =
        wob + (size_t)b * 16384 + (size_t)(m0 + mR) * DM + g * 8;
    const unsigned short* __restrict__ B = ht + (size_t)b * 65536 + g * 8;

    f32x4 C0 = {0.f,0.f,0.f,0.f}, C1 = {0.f,0.f,0.f,0.f};
    #pragma unroll
    for (int kk = 0; kk < 4; ++kk) {
        const bf16x8 aW = *(const bf16x8*)(A + kk * 32);
        const bf16x8 b0 = *(const bf16x8*)(B + (size_t)(n0 + mR) * DM + kk * 32);
        const bf16x8 b1 = *(const bf16x8*)(B + (size_t)(n0 + 16 + mR) * DM + kk * 32);
        C0 = MFMA(aW, b0, C0, 0, 0, 0);
        C1 = MFMA(aW, b1, C1, 0, 0, 0);
    }

    float* __restrict__ ob = out + (size_t)b * 65536 + (size_t)(m0 + 4 * g) * LL;
    #pragma unroll
    for (int i = 0; i < 4; ++i) {
        ob[(size_t)i * LL + n0 + mR]      = C0[i];
        ob[(size_t)i * LL + n0 + 16 + mR] = C1[i];
    }
}

extern "C" void kernel_launch(void* const* d_in, const int* in_sizes, int n_in,
                              void* d_out, int out_size, void* d_ws, size_t ws_size,
                              hipStream_t stream) {
    const float* x  = (const float*)d_in[0];
    const float* Wq = (const float*)d_in[1];
    const float* Wk = (const float*)d_in[2];
    const float* Wv = (const float*)d_in[3];
    const float* Wo = (const float*)d_in[4];
    float* out = (float*)d_out;

    char* ws = (char*)d_ws;
    unsigned short* xthi = (unsigned short*)(ws + XTH_OFF);
    unsigned short* xtlo = (unsigned short*)(ws + XTL_OFF);
    unsigned short* whi  = (unsigned short*)(ws + WHI_OFF);
    unsigned short* wlo  = (unsigned short*)(ws + WLO_OFF);
    unsigned short* wob  = (unsigned short*)(ws + WOB_OFF);
    unsigned short* qb   = (unsigned short*)(ws + QB_OFF);
    unsigned short* kb   = (unsigned short*)(ws + KB_OFF);
    unsigned short* vb   = (unsigned short*)(ws + VB_OFF);
    unsigned short* ht   = (unsigned short*)(ws + HT_OFF);

    prep     <<<1440,    256, 0, stream>>>(x, Wq, Wk, Wv, Wo, xthi, xtlo, whi, wlo, wob);
    qkv_mfma <<<HB * 6,  256, 0, stream>>>(xthi, xtlo, whi, wlo, qb, kb, vb);
    attn_mfma<<<HB * 8,  256, 0, stream>>>(qb, kb, vb, ht);
    out_mfma <<<NB * 32, 256, 0, stream>>>(wob, ht, out);
}